// Round 27
// baseline (225.464 us; speedup 1.0000x reference)
//
#include <hip/hip_runtime.h>

#define N_NODES 20000
#define N_EDGES 320000
#define C 64
#define NATTR 10
#define MSG_DIM 576      // C*(1+3+5)
#define WC_COLS 192      // 3*C
#define PRE 12           // per-wave edge capacity via LDS staging
#define REC 20           // merged record: ef[0..8) ea[8..17) snd@17 pad[18,19]

// ---------------------------------------------------------------------------
// Kernel 1: receiver histogram (1250*256 == N_EDGES exactly).
// ---------------------------------------------------------------------------
__global__ void hist_kernel(const int* __restrict__ eidx, int* __restrict__ counts) {
    const int e = blockIdx.x * 256 + threadIdx.x;
    atomicAdd(&counts[eidx[N_EDGES + e]], 1);
}

// ---------------------------------------------------------------------------
// Kernel 2 (FUSED 1-block): prefix scan + radial collapse + rec pad zeroing.
// ---------------------------------------------------------------------------
#define SCAN_PER 20   // 1024 * 20 = 20480 >= 20000
__global__ __launch_bounds__(1024) void scan_radial_kernel(
        const int* __restrict__ counts,
        int* __restrict__ start, int* __restrict__ cursor,
        const float* __restrict__ Wr0, const float* __restrict__ Wr1,
        const float* __restrict__ Wr2, const float* __restrict__ Wr3,
        float* __restrict__ Wc, float* __restrict__ rec) {
    __shared__ int wsum[16];
    __shared__ float T[8 * 64];
    __shared__ float T2[8 * 64];
    const int t = threadIdx.x, lane = t & 63, w = t >> 6;
    const float s0r = 0.35355339059327373f;  // 1/sqrt(8)
    const float s1r = 0.125f;                // 1/8

    const int base = t * SCAN_PER;
    int v[SCAN_PER];
    int s = 0;
    #pragma unroll
    for (int j = 0; j < SCAN_PER; ++j) {
        const int idx = base + j;
        v[j] = (idx < N_NODES) ? counts[idx] : 0;
        s += v[j];
    }
    int sc = s;
    #pragma unroll
    for (int off = 1; off < 64; off <<= 1) {
        int up = __shfl_up(sc, off);
        if (lane >= off) sc += up;
    }
    if (lane == 63) wsum[w] = sc;
    if (t < 16) rec[(size_t)(N_EDGES + t) * REC + 17] = 0.f;
    for (int i = t; i < 8 * 64; i += 1024) {
        int r = i >> 6, c2 = i & 63;
        float acc = 0.f;
        for (int k = 0; k < 64; ++k) acc += Wr0[r * 64 + k] * Wr1[k * 64 + c2];
        T[i] = acc * (s0r * s1r);
    }
    __syncthreads();
    if (t == 0) {
        int a = 0;
        #pragma unroll
        for (int i = 0; i < 16; ++i) { int x = wsum[i]; wsum[i] = a; a += x; }
    }
    for (int i = t; i < 8 * 64; i += 1024) {
        int r = i >> 6, c2 = i & 63;
        float acc = 0.f;
        for (int k = 0; k < 64; ++k) acc += T[r * 64 + k] * Wr2[k * 64 + c2];
        T2[i] = acc * s1r;
    }
    __syncthreads();
    int a = wsum[w] + (sc - s);   // exclusive prefix for this thread
    #pragma unroll
    for (int j = 0; j < SCAN_PER; ++j) {
        const int idx = base + j;
        if (idx < N_NODES) {
            start[idx] = a;
            cursor[idx] = a;
            a += v[j];
        }
    }
    for (int i = t; i < 8 * WC_COLS; i += 1024) {
        int r = i / WC_COLS, c2 = i % WC_COLS;
        float acc = 0.f;
        for (int k = 0; k < 64; ++k) acc += T2[r * 64 + k] * Wr3[k * WC_COLS + c2];
        Wc[i] = acc * s1r;
    }
}

// ---------------------------------------------------------------------------
// Kernel 3 (3-WAY MERGED): blocks [0,1250) counting-sort scatter;
// [1250,2500) node_linear; [2500,3125) skip (computes its OWN h slice
// in-block so it doesn't depend on node_linear -> all three independent).
// Reg-heavy skip rides with occupancy-insensitive scatter/nl, keeping the
// critical-path gather kernel pure at 44 VGPR.
// ---------------------------------------------------------------------------
__global__ __launch_bounds__(256) void scatter_nl_skip(
        const int* __restrict__ eidx,
        const float* __restrict__ ef,
        const float* __restrict__ ea,
        int* __restrict__ cursor,
        float* __restrict__ rec,
        const float* __restrict__ nf,
        const float* __restrict__ W,
        float* __restrict__ h,
        const float* __restrict__ attrs,
        const float* __restrict__ Wskip,   // 64*10*64
        float* __restrict__ sc) {
    __shared__ float Ws[64 * 64];        // 16 KB (nl + skip)
    __shared__ float row[4][64];         // 1 KB
    __shared__ float hl[32 * 64];        // 8 KB (skip only)
    const int t = threadIdx.x;

    if (blockIdx.x < 1250) {
        // ---- scatter: one edge per thread ----
        const int e = blockIdx.x * 256 + t;
        const int r = eidx[N_EDGES + e];
        const int s = eidx[e];
        const int pos = atomicAdd(&cursor[r], 1);
        const float4* f4 = reinterpret_cast<const float4*>(ef + (size_t)e * 8);
        const float* y = ea + (size_t)e * 9;
        float4* o = reinterpret_cast<float4*>(rec + (size_t)pos * REC);
        o[0] = f4[0];
        o[1] = f4[1];
        o[2] = make_float4(y[0], y[1], y[2], y[3]);
        o[3] = make_float4(y[4], y[5], y[6], y[7]);
        o[4] = make_float4(y[8], __int_as_float(s), 0.f, 0.f);
        return;
    }

    const int lane = t & 63, wv = t >> 6;
    for (int i = t; i < 4096; i += 256) Ws[i] = W[i] * 0.125f;
    __syncthreads();

    if (blockIdx.x < 2500) {
        // ---- node_linear: 16 nodes per block ----
        const int base = (blockIdx.x - 1250) * 16;
        #pragma unroll 1
        for (int it = 0; it < 4; ++it) {
            const int n = base + it * 4 + wv;
            row[wv][lane] = nf[(size_t)n * 64 + lane];
            float acc = 0.f;
            #pragma unroll
            for (int k = 0; k < 64; ++k) acc += row[wv][k] * Ws[k * 64 + lane];
            h[(size_t)n * 64 + lane] = acc;
        }
        return;
    }

    // ---- skip: 32 nodes/block; computes its own h slice first ----
    const int base = (blockIdx.x - 2500) * 32;
    #pragma unroll 1
    for (int it = 0; it < 8; ++it) {
        const int nl = it * 4 + wv;
        const int n = base + nl;
        row[wv][lane] = nf[(size_t)n * 64 + lane];
        float acc = 0.f;
        #pragma unroll
        for (int k = 0; k < 64; ++k) acc += row[wv][k] * Ws[k * 64 + lane];
        hl[nl * 64 + lane] = acc;
    }
    float alr[8][NATTR];
    #pragma unroll
    for (int i = 0; i < 8; ++i) {
        const float* ap = attrs + (size_t)(base + wv + 4 * i) * NATTR;
        #pragma unroll
        for (int v = 0; v < NATTR; ++v) alr[i][v] = ap[v];
    }
    float acc[8] = {0.f, 0.f, 0.f, 0.f, 0.f, 0.f, 0.f, 0.f};
    __syncthreads();
    #pragma unroll 1
    for (int u = 0; u < 64; ++u) {
        float tmp[8] = {0.f, 0.f, 0.f, 0.f, 0.f, 0.f, 0.f, 0.f};
        #pragma unroll
        for (int v = 0; v < NATTR; ++v) {
            const float wk = Wskip[(u * NATTR + v) * 64 + lane];
            #pragma unroll
            for (int i = 0; i < 8; ++i) tmp[i] += alr[i][v] * wk;
        }
        #pragma unroll
        for (int i = 0; i < 8; ++i)
            acc[i] += hl[(wv + 4 * i) * 64 + u] * tmp[i];
    }
    const float scale = 0.03952847075210474f;  // 1/sqrt(640)
    #pragma unroll
    for (int i = 0; i < 8; ++i)
        sc[(size_t)(base + wv + 4 * i) * 64 + lane] = acc[i] * scale;
}

// ---------------------------------------------------------------------------
// Kernel 4: gather_fused PURE (r23/r25 verbatim: 88us, VGPR 44, occ 44%).
// ---------------------------------------------------------------------------
__global__ __launch_bounds__(256) void gather_fused(
                              const float* __restrict__ rec,   // (E+16) x REC
                              const float* __restrict__ h,     // N x 64
                              const float* __restrict__ Wc,    // 8 x 192
                              const float* __restrict__ Wmsg,  // 3*64*64
                              const int* __restrict__ start,
                              const int* __restrict__ counts,
                              float* __restrict__ out) {       // N x 576 final
    __shared__ float part[2][9][64];
    __shared__ __align__(16) float erec[4][PRE * REC];   // 4 x 240 floats
    const int t = threadIdx.x, lane = t & 63, wv = t >> 6;
    const int g = wv >> 1;               // node slot within block (0,1)
    const int half = wv & 1;             // which half of the edge list
    const int n = blockIdx.x * 2 + g;    // grid is exactly N/2

    float wc0[8], wc1[8], wc2[8];
    #pragma unroll
    for (int k = 0; k < 8; ++k) {
        wc0[k] = Wc[k * WC_COLS + lane];
        wc1[k] = Wc[k * WC_COLS + 64 + lane];
        wc2[k] = Wc[k * WC_COLS + 128 + lane];
    }

    const int s0 = start[n], cnt = counts[n];
    const int jbeg = half ? (cnt >> 1) : 0;
    const int jend = half ? cnt : (cnt >> 1);
    const int m = jend - jbeg;
    const int base = s0 + jbeg;

    if (lane < PRE * REC / 4) {  // 60 lanes: 12 records in one coalesced load
        const float4 v = *reinterpret_cast<const float4*>(
            rec + (size_t)base * REC + lane * 4);
        *reinterpret_cast<float4*>(&erec[wv][lane * 4]) = v;
    }
    __syncthreads();

    float p0 = 0.f;
    float p1[3] = {0.f, 0.f, 0.f};
    float p2[5] = {0.f, 0.f, 0.f, 0.f, 0.f};

    const int P = (m < PRE) ? m : PRE;
    int snd[PRE];
    #pragma unroll
    for (int b = 0; b < PRE; ++b) snd[b] = __float_as_int(erec[wv][b * REC + 17]);
    float xs[PRE];
    #pragma unroll
    for (int b = 0; b < PRE; ++b) {
        const int sb = (b < P) ? snd[b] : snd[0];
        xs[b] = h[(size_t)sb * 64 + lane];
    }

    #pragma unroll
    for (int j = 0; j < PRE; ++j) {
        if (j < P) {   // wave-uniform predicate
            const float* er = &erec[wv][j * REC];
            const float4 e0 = *reinterpret_cast<const float4*>(er);
            const float4 e1 = *reinterpret_cast<const float4*>(er + 4);
            const float4 ya = *reinterpret_cast<const float4*>(er + 8);
            const float4 yb = *reinterpret_cast<const float4*>(er + 12);
            const float  y8 = er[16];
            const float* fk = reinterpret_cast<const float*>(&e0);
            const float* gk = reinterpret_cast<const float*>(&e1);
            float w0 = fk[0] * wc0[0], w1 = fk[0] * wc1[0], w2 = fk[0] * wc2[0];
            #pragma unroll
            for (int k = 1; k < 4; ++k) {
                w0 += fk[k] * wc0[k]; w1 += fk[k] * wc1[k]; w2 += fk[k] * wc2[k];
            }
            #pragma unroll
            for (int k = 0; k < 4; ++k) {
                w0 += gk[k] * wc0[k + 4]; w1 += gk[k] * wc1[k + 4]; w2 += gk[k] * wc2[k + 4];
            }
            const float b0 = xs[j] * w0, b1 = xs[j] * w1, b2 = xs[j] * w2;
            p0    += b0 * ya.x;
            p1[0] += b1 * ya.y; p1[1] += b1 * ya.z; p1[2] += b1 * ya.w;
            p2[0] += b2 * yb.x; p2[1] += b2 * yb.y; p2[2] += b2 * yb.z;
            p2[3] += b2 * yb.w; p2[4] += b2 * y8;
        }
    }
    for (int j = PRE; j < m; ++j) {   // rare tail m > PRE: direct global
        const float4* q = reinterpret_cast<const float4*>(rec + (size_t)(base + j) * REC);
        const float4 fa = q[0], fb = q[1];
        const float4 ya = q[2], yb = q[3], yc = q[4];
        const int snd_t = __float_as_int(yc.y);
        const float xs_t = h[(size_t)snd_t * 64 + lane];
        const float* fk = reinterpret_cast<const float*>(&fa);
        const float* gk = reinterpret_cast<const float*>(&fb);
        float w0 = fk[0] * wc0[0], w1 = fk[0] * wc1[0], w2 = fk[0] * wc2[0];
        #pragma unroll
        for (int k = 1; k < 4; ++k) {
            w0 += fk[k] * wc0[k]; w1 += fk[k] * wc1[k]; w2 += fk[k] * wc2[k];
        }
        #pragma unroll
        for (int k = 0; k < 4; ++k) {
            w0 += gk[k] * wc0[k + 4]; w1 += gk[k] * wc1[k + 4]; w2 += gk[k] * wc2[k + 4];
        }
        const float b0 = xs_t * w0, b1 = xs_t * w1, b2 = xs_t * w2;
        p0    += b0 * ya.x;
        p1[0] += b1 * ya.y; p1[1] += b1 * ya.z; p1[2] += b1 * ya.w;
        p2[0] += b2 * yb.x; p2[1] += b2 * yb.y; p2[2] += b2 * yb.z;
        p2[3] += b2 * yb.w; p2[4] += b2 * yc.x;
    }

    // ---- combine halves into part[g][m][u] (u = lane) ----
    if (half) {
        part[g][0][lane] = p0;
        #pragma unroll
        for (int m2 = 0; m2 < 3; ++m2) part[g][1 + m2][lane] = p1[m2];
        #pragma unroll
        for (int m2 = 0; m2 < 5; ++m2) part[g][4 + m2][lane] = p2[m2];
    }
    __syncthreads();
    if (!half) {
        part[g][0][lane] += p0;
        #pragma unroll
        for (int m2 = 0; m2 < 3; ++m2) part[g][1 + m2][lane] += p1[m2];
        #pragma unroll
        for (int m2 = 0; m2 < 5; ++m2) part[g][4 + m2][lane] += p2[m2];
    }
    __syncthreads();

    // ---- epilogue: in-block W_msg transform; lane = output channel v ----
    const float scale = 1.f / 128.f;  // 1/(sqrt(64)*16)
    float* op = out + (size_t)n * MSG_DIM + lane * 9;
    if (!half) {
        float o0 = 0.f, o1 = 0.f, o2 = 0.f, o3 = 0.f;
        #pragma unroll 8
        for (int u = 0; u < 64; ++u) {
            const float wv0 = Wmsg[u * 64 + lane];
            const float wv1 = Wmsg[4096 + u * 64 + lane];
            o0 += part[g][0][u] * wv0;
            o1 += part[g][1][u] * wv1;
            o2 += part[g][2][u] * wv1;
            o3 += part[g][3][u] * wv1;
        }
        op[0] = o0 * scale;
        op[1] = o1 * scale;
        op[2] = o2 * scale;
        op[3] = o3 * scale;
    } else {
        float o4 = 0.f, o5 = 0.f, o6 = 0.f, o7 = 0.f, o8 = 0.f;
        #pragma unroll 8
        for (int u = 0; u < 64; ++u) {
            const float wv2 = Wmsg[8192 + u * 64 + lane];
            o4 += part[g][4][u] * wv2;
            o5 += part[g][5][u] * wv2;
            o6 += part[g][6][u] * wv2;
            o7 += part[g][7][u] * wv2;
            o8 += part[g][8][u] * wv2;
        }
        op[4] = o4 * scale;
        op[5] = o5 * scale;
        op[6] = o6 * scale;
        op[7] = o7 * scale;
        op[8] = o8 * scale;
    }
}

// ---------------------------------------------------------------------------
extern "C" void kernel_launch(void* const* d_in, const int* in_sizes, int n_in,
                              void* d_out, int out_size, void* d_ws, size_t ws_size,
                              hipStream_t stream) {
    const float* node_attrs = (const float*)d_in[0];
    const float* node_feats = (const float*)d_in[1];
    const float* edge_attrs = (const float*)d_in[2];
    const float* edge_feats = (const float*)d_in[3];
    const int*   edge_index = (const int*)d_in[4];
    const float* W_lin1 = (const float*)d_in[5];
    const float* W_r0 = (const float*)d_in[6];
    const float* W_r1 = (const float*)d_in[7];
    const float* W_r2 = (const float*)d_in[8];
    const float* W_r3 = (const float*)d_in[9];
    const float* W_msg = (const float*)d_in[10];
    const float* W_skip = (const float*)d_in[11];

    float* out = (float*)d_out;                       // N x 576 final
    float* sc  = out + (size_t)N_NODES * MSG_DIM;     // N x 64

    float* wsf = (float*)d_ws;
    float* Wc = wsf;                          // 2048 floats
    float* h  = wsf + 2048;                   // N*64
    int* wsi   = (int*)(wsf + 2048 + (size_t)N_NODES * 64);
    int* counts = wsi;                        // N
    int* start  = wsi + N_NODES;              // N
    int* cursor = wsi + 2 * N_NODES;          // N
    float* rec  = (float*)(wsi + 3 * N_NODES);        // (E+16) * REC floats

    hipMemsetAsync(counts, 0, N_NODES * sizeof(int), stream);
    hist_kernel<<<1250, 256, 0, stream>>>(edge_index, counts);
    scan_radial_kernel<<<1, 1024, 0, stream>>>(counts, start, cursor,
                                               W_r0, W_r1, W_r2, W_r3, Wc, rec);
    scatter_nl_skip<<<3125, 256, 0, stream>>>(
        edge_index, edge_feats, edge_attrs, cursor, rec,
        node_feats, W_lin1, h,
        node_attrs, W_skip, sc);
    gather_fused<<<N_NODES / 2, 256, 0, stream>>>(
        rec, h, Wc, W_msg, start, counts, out);
}

// Round 28
// 203.505 us; speedup vs baseline: 1.1079x; 1.1079x over previous
//
#include <hip/hip_runtime.h>

#define N_NODES 20000
#define N_EDGES 320000
#define C 64
#define NATTR 10
#define MSG_DIM 576      // C*(1+3+5)
#define WC_COLS 192      // 3*C
#define PRE 12           // per-wave edge capacity via LDS staging
#define REC 20           // merged record: ef[0..8) ea[8..17) snd@17 pad[18,19]

// ---------------------------------------------------------------------------
// Kernel 1: receiver histogram (standalone; 1250*256 == N_EDGES exactly).
// ---------------------------------------------------------------------------
__global__ void hist_kernel(const int* __restrict__ eidx, int* __restrict__ counts) {
    const int e = blockIdx.x * 256 + threadIdx.x;
    atomicAdd(&counts[eidx[N_EDGES + e]], 1);
}

// ---------------------------------------------------------------------------
// Kernel 2 (FUSED 1-block): prefix scan + radial collapse + rec pad zeroing.
// ---------------------------------------------------------------------------
#define SCAN_PER 20   // 1024 * 20 = 20480 >= 20000
__global__ __launch_bounds__(1024) void scan_radial_kernel(
        const int* __restrict__ counts,
        int* __restrict__ start, int* __restrict__ cursor,
        const float* __restrict__ Wr0, const float* __restrict__ Wr1,
        const float* __restrict__ Wr2, const float* __restrict__ Wr3,
        float* __restrict__ Wc, float* __restrict__ rec) {
    __shared__ int wsum[16];
    __shared__ float T[8 * 64];
    __shared__ float T2[8 * 64];
    const int t = threadIdx.x, lane = t & 63, w = t >> 6;
    const float s0r = 0.35355339059327373f;  // 1/sqrt(8)
    const float s1r = 0.125f;                // 1/8

    const int base = t * SCAN_PER;
    int v[SCAN_PER];
    int s = 0;
    #pragma unroll
    for (int j = 0; j < SCAN_PER; ++j) {
        const int idx = base + j;
        v[j] = (idx < N_NODES) ? counts[idx] : 0;
        s += v[j];
    }
    int sc = s;
    #pragma unroll
    for (int off = 1; off < 64; off <<= 1) {
        int up = __shfl_up(sc, off);
        if (lane >= off) sc += up;
    }
    if (lane == 63) wsum[w] = sc;
    if (t < 16) rec[(size_t)(N_EDGES + t) * REC + 17] = 0.f;
    for (int i = t; i < 8 * 64; i += 1024) {
        int r = i >> 6, c2 = i & 63;
        float acc = 0.f;
        for (int k = 0; k < 64; ++k) acc += Wr0[r * 64 + k] * Wr1[k * 64 + c2];
        T[i] = acc * (s0r * s1r);
    }
    __syncthreads();
    if (t == 0) {
        int a = 0;
        #pragma unroll
        for (int i = 0; i < 16; ++i) { int x = wsum[i]; wsum[i] = a; a += x; }
    }
    for (int i = t; i < 8 * 64; i += 1024) {
        int r = i >> 6, c2 = i & 63;
        float acc = 0.f;
        for (int k = 0; k < 64; ++k) acc += T[r * 64 + k] * Wr2[k * 64 + c2];
        T2[i] = acc * s1r;
    }
    __syncthreads();
    int a = wsum[w] + (sc - s);   // exclusive prefix for this thread
    #pragma unroll
    for (int j = 0; j < SCAN_PER; ++j) {
        const int idx = base + j;
        if (idx < N_NODES) {
            start[idx] = a;
            cursor[idx] = a;
            a += v[j];
        }
    }
    for (int i = t; i < 8 * WC_COLS; i += 1024) {
        int r = i / WC_COLS, c2 = i % WC_COLS;
        float acc = 0.f;
        for (int k = 0; k < 64; ++k) acc += T2[r * 64 + k] * Wr3[k * WC_COLS + c2];
        Wc[i] = acc * s1r;
    }
}

// ---------------------------------------------------------------------------
// Kernel 3 (MERGED): blocks [0,1250) counting-sort scatter (memory/atomic);
// blocks [1250,2500) node_linear h = nf @ (W/8) (VALU/LDS). Independent
// producers for the next dispatch — co-scheduled to overlap.
// ---------------------------------------------------------------------------
__global__ __launch_bounds__(256) void scatter_nl(
        const int* __restrict__ eidx,
        const float* __restrict__ ef,
        const float* __restrict__ ea,
        int* __restrict__ cursor,
        float* __restrict__ rec,
        const float* __restrict__ nf,
        const float* __restrict__ W,
        float* __restrict__ h) {
    __shared__ float Ws[64 * 64];
    __shared__ float row[4][64];
    const int t = threadIdx.x;

    if (blockIdx.x < 1250) {
        // ---- scatter: one edge per thread ----
        const int e = blockIdx.x * 256 + t;
        const int r = eidx[N_EDGES + e];
        const int s = eidx[e];
        const int pos = atomicAdd(&cursor[r], 1);
        const float4* f4 = reinterpret_cast<const float4*>(ef + (size_t)e * 8);
        const float* y = ea + (size_t)e * 9;
        float4* o = reinterpret_cast<float4*>(rec + (size_t)pos * REC);
        o[0] = f4[0];
        o[1] = f4[1];
        o[2] = make_float4(y[0], y[1], y[2], y[3]);
        o[3] = make_float4(y[4], y[5], y[6], y[7]);
        o[4] = make_float4(y[8], __int_as_float(s), 0.f, 0.f);
        return;
    }

    // ---- node_linear: 16 nodes per block ----
    const int lane = t & 63, wv = t >> 6;
    for (int i = t; i < 4096; i += 256) Ws[i] = W[i] * 0.125f;
    __syncthreads();
    const int base = (blockIdx.x - 1250) * 16;
    #pragma unroll 1
    for (int it = 0; it < 4; ++it) {
        const int n = base + it * 4 + wv;
        row[wv][lane] = nf[(size_t)n * 64 + lane];
        float acc = 0.f;
        #pragma unroll
        for (int k = 0; k < 64; ++k) acc += row[wv][k] * Ws[k * 64 + lane];
        h[(size_t)n * 64 + lane] = acc;
    }
}

// ---------------------------------------------------------------------------
// Kernel 4 (MERGED): blocks [0,625) skip contraction (VALU-bound, W_skip
// direct from global, LDS 8.4 KB union); blocks [625,10625) the proven r23
// gather_fused. Skip overlaps under gather's latency-bound run.
// ---------------------------------------------------------------------------
__global__ __launch_bounds__(256) void gather_skip(
                              const float* __restrict__ rec,   // (E+16) x REC
                              const float* __restrict__ h,     // N x 64
                              const float* __restrict__ Wc,    // 8 x 192
                              const float* __restrict__ Wmsg,  // 3*64*64
                              const int* __restrict__ start,
                              const int* __restrict__ counts,
                              float* __restrict__ out,         // N x 576 final
                              const float* __restrict__ attrs,
                              const float* __restrict__ Wskip, // 64*10*64
                              float* __restrict__ sc) {        // N x 64
    __shared__ __align__(16) float smem[2112];   // union: gather 2112f / skip 2048f
    const int t = threadIdx.x, lane = t & 63, wv = t >> 6;

    if (blockIdx.x < 625) {
        // ---- skip: 32 nodes/block (8 per thread), W_skip direct global ----
        float* hl = smem;   // 2048 floats
        const int base = blockIdx.x * 32;
        {
            const float4* src = reinterpret_cast<const float4*>(h + (size_t)base * 64);
            float4* dst = reinterpret_cast<float4*>(hl);
            dst[t] = src[t];
            dst[t + 256] = src[t + 256];
        }
        float alr[8][NATTR];
        #pragma unroll
        for (int i = 0; i < 8; ++i) {
            const float* ap = attrs + (size_t)(base + wv + 4 * i) * NATTR;
            #pragma unroll
            for (int v = 0; v < NATTR; ++v) alr[i][v] = ap[v];
        }
        float acc[8] = {0.f, 0.f, 0.f, 0.f, 0.f, 0.f, 0.f, 0.f};
        __syncthreads();
        #pragma unroll 1
        for (int u = 0; u < 64; ++u) {
            float tmp[8] = {0.f, 0.f, 0.f, 0.f, 0.f, 0.f, 0.f, 0.f};
            #pragma unroll
            for (int v = 0; v < NATTR; ++v) {
                const float wk = Wskip[(u * NATTR + v) * 64 + lane];
                #pragma unroll
                for (int i = 0; i < 8; ++i) tmp[i] += alr[i][v] * wk;
            }
            #pragma unroll
            for (int i = 0; i < 8; ++i)
                acc[i] += hl[(wv + 4 * i) * 64 + u] * tmp[i];
        }
        const float scale = 0.03952847075210474f;  // 1/sqrt(640)
        #pragma unroll
        for (int i = 0; i < 8; ++i)
            sc[(size_t)(base + wv + 4 * i) * 64 + lane] = acc[i] * scale;
        return;
    }

    // ---- gather_fused (r23 verbatim, smem-union layout) ----
    float (*part)[9][64] = reinterpret_cast<float(*)[9][64]>(smem);          // 1152 f
    float (*erec)[PRE * REC] = reinterpret_cast<float(*)[PRE * REC]>(smem + 1152); // 960 f
    const int g = wv >> 1;               // node slot within block (0,1)
    const int half = wv & 1;             // which half of the edge list
    const int n = (blockIdx.x - 625) * 2 + g;

    float wc0[8], wc1[8], wc2[8];
    #pragma unroll
    for (int k = 0; k < 8; ++k) {
        wc0[k] = Wc[k * WC_COLS + lane];
        wc1[k] = Wc[k * WC_COLS + 64 + lane];
        wc2[k] = Wc[k * WC_COLS + 128 + lane];
    }

    const int s0 = start[n], cnt = counts[n];
    const int jbeg = half ? (cnt >> 1) : 0;
    const int jend = half ? cnt : (cnt >> 1);
    const int m = jend - jbeg;
    const int base = s0 + jbeg;

    if (lane < PRE * REC / 4) {  // 60 lanes: 12 records in one coalesced load
        const float4 v = *reinterpret_cast<const float4*>(
            rec + (size_t)base * REC + lane * 4);
        *reinterpret_cast<float4*>(&erec[wv][lane * 4]) = v;
    }
    __syncthreads();

    float p0 = 0.f;
    float p1[3] = {0.f, 0.f, 0.f};
    float p2[5] = {0.f, 0.f, 0.f, 0.f, 0.f};

    const int P = (m < PRE) ? m : PRE;
    int snd[PRE];
    #pragma unroll
    for (int b = 0; b < PRE; ++b) snd[b] = __float_as_int(erec[wv][b * REC + 17]);
    float xs[PRE];
    #pragma unroll
    for (int b = 0; b < PRE; ++b) {
        const int sb = (b < P) ? snd[b] : snd[0];
        xs[b] = h[(size_t)sb * 64 + lane];
    }

    #pragma unroll
    for (int j = 0; j < PRE; ++j) {
        if (j < P) {   // wave-uniform predicate
            const float* er = &erec[wv][j * REC];
            const float4 e0 = *reinterpret_cast<const float4*>(er);
            const float4 e1 = *reinterpret_cast<const float4*>(er + 4);
            const float4 ya = *reinterpret_cast<const float4*>(er + 8);
            const float4 yb = *reinterpret_cast<const float4*>(er + 12);
            const float  y8 = er[16];
            const float* fk = reinterpret_cast<const float*>(&e0);
            const float* gk = reinterpret_cast<const float*>(&e1);
            float w0 = fk[0] * wc0[0], w1 = fk[0] * wc1[0], w2 = fk[0] * wc2[0];
            #pragma unroll
            for (int k = 1; k < 4; ++k) {
                w0 += fk[k] * wc0[k]; w1 += fk[k] * wc1[k]; w2 += fk[k] * wc2[k];
            }
            #pragma unroll
            for (int k = 0; k < 4; ++k) {
                w0 += gk[k] * wc0[k + 4]; w1 += gk[k] * wc1[k + 4]; w2 += gk[k] * wc2[k + 4];
            }
            const float b0 = xs[j] * w0, b1 = xs[j] * w1, b2 = xs[j] * w2;
            p0    += b0 * ya.x;
            p1[0] += b1 * ya.y; p1[1] += b1 * ya.z; p1[2] += b1 * ya.w;
            p2[0] += b2 * yb.x; p2[1] += b2 * yb.y; p2[2] += b2 * yb.z;
            p2[3] += b2 * yb.w; p2[4] += b2 * y8;
        }
    }
    for (int j = PRE; j < m; ++j) {   // rare tail m > PRE: direct global
        const float4* q = reinterpret_cast<const float4*>(rec + (size_t)(base + j) * REC);
        const float4 fa = q[0], fb = q[1];
        const float4 ya = q[2], yb = q[3], yc = q[4];
        const int snd_t = __float_as_int(yc.y);
        const float xs_t = h[(size_t)snd_t * 64 + lane];
        const float* fk = reinterpret_cast<const float*>(&fa);
        const float* gk = reinterpret_cast<const float*>(&fb);
        float w0 = fk[0] * wc0[0], w1 = fk[0] * wc1[0], w2 = fk[0] * wc2[0];
        #pragma unroll
        for (int k = 1; k < 4; ++k) {
            w0 += fk[k] * wc0[k]; w1 += fk[k] * wc1[k]; w2 += fk[k] * wc2[k];
        }
        #pragma unroll
        for (int k = 0; k < 4; ++k) {
            w0 += gk[k] * wc0[k + 4]; w1 += gk[k] * wc1[k + 4]; w2 += gk[k] * wc2[k + 4];
        }
        const float b0 = xs_t * w0, b1 = xs_t * w1, b2 = xs_t * w2;
        p0    += b0 * ya.x;
        p1[0] += b1 * ya.y; p1[1] += b1 * ya.z; p1[2] += b1 * ya.w;
        p2[0] += b2 * yb.x; p2[1] += b2 * yb.y; p2[2] += b2 * yb.z;
        p2[3] += b2 * yb.w; p2[4] += b2 * yc.x;
    }

    // ---- combine halves into part[g][m][u] (u = lane) ----
    if (half) {
        part[g][0][lane] = p0;
        #pragma unroll
        for (int m2 = 0; m2 < 3; ++m2) part[g][1 + m2][lane] = p1[m2];
        #pragma unroll
        for (int m2 = 0; m2 < 5; ++m2) part[g][4 + m2][lane] = p2[m2];
    }
    __syncthreads();
    if (!half) {
        part[g][0][lane] += p0;
        #pragma unroll
        for (int m2 = 0; m2 < 3; ++m2) part[g][1 + m2][lane] += p1[m2];
        #pragma unroll
        for (int m2 = 0; m2 < 5; ++m2) part[g][4 + m2][lane] += p2[m2];
    }
    __syncthreads();

    // ---- epilogue: in-block W_msg transform; lane = output channel v ----
    const float scale = 1.f / 128.f;  // 1/(sqrt(64)*16)
    float* op = out + (size_t)n * MSG_DIM + lane * 9;
    if (!half) {
        float o0 = 0.f, o1 = 0.f, o2 = 0.f, o3 = 0.f;
        #pragma unroll 8
        for (int u = 0; u < 64; ++u) {
            const float wv0 = Wmsg[u * 64 + lane];
            const float wv1 = Wmsg[4096 + u * 64 + lane];
            o0 += part[g][0][u] * wv0;
            o1 += part[g][1][u] * wv1;
            o2 += part[g][2][u] * wv1;
            o3 += part[g][3][u] * wv1;
        }
        op[0] = o0 * scale;
        op[1] = o1 * scale;
        op[2] = o2 * scale;
        op[3] = o3 * scale;
    } else {
        float o4 = 0.f, o5 = 0.f, o6 = 0.f, o7 = 0.f, o8 = 0.f;
        #pragma unroll 8
        for (int u = 0; u < 64; ++u) {
            const float wv2 = Wmsg[8192 + u * 64 + lane];
            o4 += part[g][4][u] * wv2;
            o5 += part[g][5][u] * wv2;
            o6 += part[g][6][u] * wv2;
            o7 += part[g][7][u] * wv2;
            o8 += part[g][8][u] * wv2;
        }
        op[4] = o4 * scale;
        op[5] = o5 * scale;
        op[6] = o6 * scale;
        op[7] = o7 * scale;
        op[8] = o8 * scale;
    }
}

// ---------------------------------------------------------------------------
extern "C" void kernel_launch(void* const* d_in, const int* in_sizes, int n_in,
                              void* d_out, int out_size, void* d_ws, size_t ws_size,
                              hipStream_t stream) {
    const float* node_attrs = (const float*)d_in[0];
    const float* node_feats = (const float*)d_in[1];
    const float* edge_attrs = (const float*)d_in[2];
    const float* edge_feats = (const float*)d_in[3];
    const int*   edge_index = (const int*)d_in[4];
    const float* W_lin1 = (const float*)d_in[5];
    const float* W_r0 = (const float*)d_in[6];
    const float* W_r1 = (const float*)d_in[7];
    const float* W_r2 = (const float*)d_in[8];
    const float* W_r3 = (const float*)d_in[9];
    const float* W_msg = (const float*)d_in[10];
    const float* W_skip = (const float*)d_in[11];

    float* out = (float*)d_out;                       // N x 576 final
    float* sc  = out + (size_t)N_NODES * MSG_DIM;     // N x 64

    float* wsf = (float*)d_ws;
    float* Wc = wsf;                          // 2048 floats
    float* h  = wsf + 2048;                   // N*64
    int* wsi   = (int*)(wsf + 2048 + (size_t)N_NODES * 64);
    int* counts = wsi;                        // N
    int* start  = wsi + N_NODES;              // N
    int* cursor = wsi + 2 * N_NODES;          // N
    float* rec  = (float*)(wsi + 3 * N_NODES);        // (E+16) * REC floats

    hipMemsetAsync(counts, 0, N_NODES * sizeof(int), stream);
    hist_kernel<<<1250, 256, 0, stream>>>(edge_index, counts);
    scan_radial_kernel<<<1, 1024, 0, stream>>>(counts, start, cursor,
                                               W_r0, W_r1, W_r2, W_r3, Wc, rec);
    scatter_nl<<<2500, 256, 0, stream>>>(
        edge_index, edge_feats, edge_attrs, cursor, rec,
        node_feats, W_lin1, h);
    gather_skip<<<10625, 256, 0, stream>>>(
        rec, h, Wc, W_msg, start, counts, out,
        node_attrs, W_skip, sc);
}

// Round 30
// 203.166 us; speedup vs baseline: 1.1098x; 1.0017x over previous
//
#include <hip/hip_runtime.h>

#define N_NODES 20000
#define N_EDGES 320000
#define C 64
#define NATTR 10
#define MSG_DIM 576      // C*(1+3+5)
#define WC_COLS 192      // 3*C
#define PRE 12           // per-wave edge capacity via LDS staging
#define REC 20           // merged record: ef[0..8) ea[8..17) snd@17 pad[18,19]

// ---------------------------------------------------------------------------
// Kernel 1: receiver histogram (standalone; 1250*256 == N_EDGES exactly).
// ---------------------------------------------------------------------------
__global__ void hist_kernel(const int* __restrict__ eidx, int* __restrict__ counts) {
    const int e = blockIdx.x * 256 + threadIdx.x;
    atomicAdd(&counts[eidx[N_EDGES + e]], 1);
}

// ---------------------------------------------------------------------------
// Kernel 2 (FUSED 1-block): prefix scan + radial collapse + rec pad zeroing.
// ---------------------------------------------------------------------------
#define SCAN_PER 20   // 1024 * 20 = 20480 >= 20000
__global__ __launch_bounds__(1024) void scan_radial_kernel(
        const int* __restrict__ counts,
        int* __restrict__ start, int* __restrict__ cursor,
        const float* __restrict__ Wr0, const float* __restrict__ Wr1,
        const float* __restrict__ Wr2, const float* __restrict__ Wr3,
        float* __restrict__ Wc, float* __restrict__ rec) {
    __shared__ int wsum[16];
    __shared__ float T[8 * 64];
    __shared__ float T2[8 * 64];
    const int t = threadIdx.x, lane = t & 63, w = t >> 6;
    const float s0r = 0.35355339059327373f;  // 1/sqrt(8)
    const float s1r = 0.125f;                // 1/8

    const int base = t * SCAN_PER;
    int v[SCAN_PER];
    int s = 0;
    #pragma unroll
    for (int j = 0; j < SCAN_PER; ++j) {
        const int idx = base + j;
        v[j] = (idx < N_NODES) ? counts[idx] : 0;
        s += v[j];
    }
    int sc = s;
    #pragma unroll
    for (int off = 1; off < 64; off <<= 1) {
        int up = __shfl_up(sc, off);
        if (lane >= off) sc += up;
    }
    if (lane == 63) wsum[w] = sc;
    if (t < 16) rec[(size_t)(N_EDGES + t) * REC + 17] = 0.f;
    for (int i = t; i < 8 * 64; i += 1024) {
        int r = i >> 6, c2 = i & 63;
        float acc = 0.f;
        for (int k = 0; k < 64; ++k) acc += Wr0[r * 64 + k] * Wr1[k * 64 + c2];
        T[i] = acc * (s0r * s1r);
    }
    __syncthreads();
    if (t == 0) {
        int a = 0;
        #pragma unroll
        for (int i = 0; i < 16; ++i) { int x = wsum[i]; wsum[i] = a; a += x; }
    }
    for (int i = t; i < 8 * 64; i += 1024) {
        int r = i >> 6, c2 = i & 63;
        float acc = 0.f;
        for (int k = 0; k < 64; ++k) acc += T[r * 64 + k] * Wr2[k * 64 + c2];
        T2[i] = acc * s1r;
    }
    __syncthreads();
    int a = wsum[w] + (sc - s);   // exclusive prefix for this thread
    #pragma unroll
    for (int j = 0; j < SCAN_PER; ++j) {
        const int idx = base + j;
        if (idx < N_NODES) {
            start[idx] = a;
            cursor[idx] = a;
            a += v[j];
        }
    }
    for (int i = t; i < 8 * WC_COLS; i += 1024) {
        int r = i / WC_COLS, c2 = i % WC_COLS;
        float acc = 0.f;
        for (int k = 0; k < 64; ++k) acc += T2[r * 64 + k] * Wr3[k * WC_COLS + c2];
        Wc[i] = acc * s1r;
    }
}

// ---------------------------------------------------------------------------
// Kernel 3 (MERGED): blocks [0,1250) counting-sort scatter (memory/atomic);
// blocks [1250,2500) node_linear h = nf @ (W/8) (VALU/LDS). Independent
// producers for the next dispatch — co-scheduled to overlap.
// ---------------------------------------------------------------------------
__global__ __launch_bounds__(256) void scatter_nl(
        const int* __restrict__ eidx,
        const float* __restrict__ ef,
        const float* __restrict__ ea,
        int* __restrict__ cursor,
        float* __restrict__ rec,
        const float* __restrict__ nf,
        const float* __restrict__ W,
        float* __restrict__ h) {
    __shared__ float Ws[64 * 64];
    __shared__ float row[4][64];
    const int t = threadIdx.x;

    if (blockIdx.x < 1250) {
        // ---- scatter: one edge per thread ----
        const int e = blockIdx.x * 256 + t;
        const int r = eidx[N_EDGES + e];
        const int s = eidx[e];
        const int pos = atomicAdd(&cursor[r], 1);
        const float4* f4 = reinterpret_cast<const float4*>(ef + (size_t)e * 8);
        const float* y = ea + (size_t)e * 9;
        float4* o = reinterpret_cast<float4*>(rec + (size_t)pos * REC);
        o[0] = f4[0];
        o[1] = f4[1];
        o[2] = make_float4(y[0], y[1], y[2], y[3]);
        o[3] = make_float4(y[4], y[5], y[6], y[7]);
        o[4] = make_float4(y[8], __int_as_float(s), 0.f, 0.f);
        return;
    }

    // ---- node_linear: 16 nodes per block ----
    const int lane = t & 63, wv = t >> 6;
    for (int i = t; i < 4096; i += 256) Ws[i] = W[i] * 0.125f;
    __syncthreads();
    const int base = (blockIdx.x - 1250) * 16;
    #pragma unroll 1
    for (int it = 0; it < 4; ++it) {
        const int n = base + it * 4 + wv;
        row[wv][lane] = nf[(size_t)n * 64 + lane];
        float acc = 0.f;
        #pragma unroll
        for (int k = 0; k < 64; ++k) acc += row[wv][k] * Ws[k * 64 + lane];
        h[(size_t)n * 64 + lane] = acc;
    }
}

// ---------------------------------------------------------------------------
// Kernel 4 (MERGED): blocks [0,625) skip contraction (VALU-bound, W_skip
// direct from global, LDS 8.4 KB union); blocks [625,10625) the proven r23
// gather_fused. Skip overlaps under gather's latency-bound run.
// ---------------------------------------------------------------------------
__global__ __launch_bounds__(256) void gather_skip(
                              const float* __restrict__ rec,   // (E+16) x REC
                              const float* __restrict__ h,     // N x 64
                              const float* __restrict__ Wc,    // 8 x 192
                              const float* __restrict__ Wmsg,  // 3*64*64
                              const int* __restrict__ start,
                              const int* __restrict__ counts,
                              float* __restrict__ out,         // N x 576 final
                              const float* __restrict__ attrs,
                              const float* __restrict__ Wskip, // 64*10*64
                              float* __restrict__ sc) {        // N x 64
    __shared__ __align__(16) float smem[2112];   // union: gather 2112f / skip 2048f
    const int t = threadIdx.x, lane = t & 63, wv = t >> 6;

    if (blockIdx.x < 625) {
        // ---- skip: 32 nodes/block (8 per thread), W_skip direct global ----
        float* hl = smem;   // 2048 floats
        const int base = blockIdx.x * 32;
        {
            const float4* src = reinterpret_cast<const float4*>(h + (size_t)base * 64);
            float4* dst = reinterpret_cast<float4*>(hl);
            dst[t] = src[t];
            dst[t + 256] = src[t + 256];
        }
        float alr[8][NATTR];
        #pragma unroll
        for (int i = 0; i < 8; ++i) {
            const float* ap = attrs + (size_t)(base + wv + 4 * i) * NATTR;
            #pragma unroll
            for (int v = 0; v < NATTR; ++v) alr[i][v] = ap[v];
        }
        float acc[8] = {0.f, 0.f, 0.f, 0.f, 0.f, 0.f, 0.f, 0.f};
        __syncthreads();
        #pragma unroll 1
        for (int u = 0; u < 64; ++u) {
            float tmp[8] = {0.f, 0.f, 0.f, 0.f, 0.f, 0.f, 0.f, 0.f};
            #pragma unroll
            for (int v = 0; v < NATTR; ++v) {
                const float wk = Wskip[(u * NATTR + v) * 64 + lane];
                #pragma unroll
                for (int i = 0; i < 8; ++i) tmp[i] += alr[i][v] * wk;
            }
            #pragma unroll
            for (int i = 0; i < 8; ++i)
                acc[i] += hl[(wv + 4 * i) * 64 + u] * tmp[i];
        }
        const float scale = 0.03952847075210474f;  // 1/sqrt(640)
        #pragma unroll
        for (int i = 0; i < 8; ++i)
            sc[(size_t)(base + wv + 4 * i) * 64 + lane] = acc[i] * scale;
        return;
    }

    // ---- gather_fused (r23 verbatim, smem-union layout) ----
    float (*part)[9][64] = reinterpret_cast<float(*)[9][64]>(smem);          // 1152 f
    float (*erec)[PRE * REC] = reinterpret_cast<float(*)[PRE * REC]>(smem + 1152); // 960 f
    const int g = wv >> 1;               // node slot within block (0,1)
    const int half = wv & 1;             // which half of the edge list
    const int n = (blockIdx.x - 625) * 2 + g;

    float wc0[8], wc1[8], wc2[8];
    #pragma unroll
    for (int k = 0; k < 8; ++k) {
        wc0[k] = Wc[k * WC_COLS + lane];
        wc1[k] = Wc[k * WC_COLS + 64 + lane];
        wc2[k] = Wc[k * WC_COLS + 128 + lane];
    }

    const int s0 = start[n], cnt = counts[n];
    const int jbeg = half ? (cnt >> 1) : 0;
    const int jend = half ? cnt : (cnt >> 1);
    const int m = jend - jbeg;
    const int base = s0 + jbeg;

    if (lane < PRE * REC / 4) {  // 60 lanes: 12 records in one coalesced load
        const float4 v = *reinterpret_cast<const float4*>(
            rec + (size_t)base * REC + lane * 4);
        *reinterpret_cast<float4*>(&erec[wv][lane * 4]) = v;
    }
    __syncthreads();

    float p0 = 0.f;
    float p1[3] = {0.f, 0.f, 0.f};
    float p2[5] = {0.f, 0.f, 0.f, 0.f, 0.f};

    const int P = (m < PRE) ? m : PRE;
    int snd[PRE];
    #pragma unroll
    for (int b = 0; b < PRE; ++b) snd[b] = __float_as_int(erec[wv][b * REC + 17]);
    float xs[PRE];
    #pragma unroll
    for (int b = 0; b < PRE; ++b) {
        const int sb = (b < P) ? snd[b] : snd[0];
        xs[b] = h[(size_t)sb * 64 + lane];
    }

    #pragma unroll
    for (int j = 0; j < PRE; ++j) {
        if (j < P) {   // wave-uniform predicate
            const float* er = &erec[wv][j * REC];
            const float4 e0 = *reinterpret_cast<const float4*>(er);
            const float4 e1 = *reinterpret_cast<const float4*>(er + 4);
            const float4 ya = *reinterpret_cast<const float4*>(er + 8);
            const float4 yb = *reinterpret_cast<const float4*>(er + 12);
            const float  y8 = er[16];
            const float* fk = reinterpret_cast<const float*>(&e0);
            const float* gk = reinterpret_cast<const float*>(&e1);
            float w0 = fk[0] * wc0[0], w1 = fk[0] * wc1[0], w2 = fk[0] * wc2[0];
            #pragma unroll
            for (int k = 1; k < 4; ++k) {
                w0 += fk[k] * wc0[k]; w1 += fk[k] * wc1[k]; w2 += fk[k] * wc2[k];
            }
            #pragma unroll
            for (int k = 0; k < 4; ++k) {
                w0 += gk[k] * wc0[k + 4]; w1 += gk[k] * wc1[k + 4]; w2 += gk[k] * wc2[k + 4];
            }
            const float b0 = xs[j] * w0, b1 = xs[j] * w1, b2 = xs[j] * w2;
            p0    += b0 * ya.x;
            p1[0] += b1 * ya.y; p1[1] += b1 * ya.z; p1[2] += b1 * ya.w;
            p2[0] += b2 * yb.x; p2[1] += b2 * yb.y; p2[2] += b2 * yb.z;
            p2[3] += b2 * yb.w; p2[4] += b2 * y8;
        }
    }
    for (int j = PRE; j < m; ++j) {   // rare tail m > PRE: direct global
        const float4* q = reinterpret_cast<const float4*>(rec + (size_t)(base + j) * REC);
        const float4 fa = q[0], fb = q[1];
        const float4 ya = q[2], yb = q[3], yc = q[4];
        const int snd_t = __float_as_int(yc.y);
        const float xs_t = h[(size_t)snd_t * 64 + lane];
        const float* fk = reinterpret_cast<const float*>(&fa);
        const float* gk = reinterpret_cast<const float*>(&fb);
        float w0 = fk[0] * wc0[0], w1 = fk[0] * wc1[0], w2 = fk[0] * wc2[0];
        #pragma unroll
        for (int k = 1; k < 4; ++k) {
            w0 += fk[k] * wc0[k]; w1 += fk[k] * wc1[k]; w2 += fk[k] * wc2[k];
        }
        #pragma unroll
        for (int k = 0; k < 4; ++k) {
            w0 += gk[k] * wc0[k + 4]; w1 += gk[k] * wc1[k + 4]; w2 += gk[k] * wc2[k + 4];
        }
        const float b0 = xs_t * w0, b1 = xs_t * w1, b2 = xs_t * w2;
        p0    += b0 * ya.x;
        p1[0] += b1 * ya.y; p1[1] += b1 * ya.z; p1[2] += b1 * ya.w;
        p2[0] += b2 * yb.x; p2[1] += b2 * yb.y; p2[2] += b2 * yb.z;
        p2[3] += b2 * yb.w; p2[4] += b2 * yc.x;
    }

    // ---- combine halves into part[g][m][u] (u = lane) ----
    if (half) {
        part[g][0][lane] = p0;
        #pragma unroll
        for (int m2 = 0; m2 < 3; ++m2) part[g][1 + m2][lane] = p1[m2];
        #pragma unroll
        for (int m2 = 0; m2 < 5; ++m2) part[g][4 + m2][lane] = p2[m2];
    }
    __syncthreads();
    if (!half) {
        part[g][0][lane] += p0;
        #pragma unroll
        for (int m2 = 0; m2 < 3; ++m2) part[g][1 + m2][lane] += p1[m2];
        #pragma unroll
        for (int m2 = 0; m2 < 5; ++m2) part[g][4 + m2][lane] += p2[m2];
    }
    __syncthreads();

    // ---- epilogue: in-block W_msg transform; lane = output channel v ----
    const float scale = 1.f / 128.f;  // 1/(sqrt(64)*16)
    float* op = out + (size_t)n * MSG_DIM + lane * 9;
    if (!half) {
        float o0 = 0.f, o1 = 0.f, o2 = 0.f, o3 = 0.f;
        #pragma unroll 8
        for (int u = 0; u < 64; ++u) {
            const float wv0 = Wmsg[u * 64 + lane];
            const float wv1 = Wmsg[4096 + u * 64 + lane];
            o0 += part[g][0][u] * wv0;
            o1 += part[g][1][u] * wv1;
            o2 += part[g][2][u] * wv1;
            o3 += part[g][3][u] * wv1;
        }
        op[0] = o0 * scale;
        op[1] = o1 * scale;
        op[2] = o2 * scale;
        op[3] = o3 * scale;
    } else {
        float o4 = 0.f, o5 = 0.f, o6 = 0.f, o7 = 0.f, o8 = 0.f;
        #pragma unroll 8
        for (int u = 0; u < 64; ++u) {
            const float wv2 = Wmsg[8192 + u * 64 + lane];
            o4 += part[g][4][u] * wv2;
            o5 += part[g][5][u] * wv2;
            o6 += part[g][6][u] * wv2;
            o7 += part[g][7][u] * wv2;
            o8 += part[g][8][u] * wv2;
        }
        op[4] = o4 * scale;
        op[5] = o5 * scale;
        op[6] = o6 * scale;
        op[7] = o7 * scale;
        op[8] = o8 * scale;
    }
}

// ---------------------------------------------------------------------------
extern "C" void kernel_launch(void* const* d_in, const int* in_sizes, int n_in,
                              void* d_out, int out_size, void* d_ws, size_t ws_size,
                              hipStream_t stream) {
    const float* node_attrs = (const float*)d_in[0];
    const float* node_feats = (const float*)d_in[1];
    const float* edge_attrs = (const float*)d_in[2];
    const float* edge_feats = (const float*)d_in[3];
    const int*   edge_index = (const int*)d_in[4];
    const float* W_lin1 = (const float*)d_in[5];
    const float* W_r0 = (const float*)d_in[6];
    const float* W_r1 = (const float*)d_in[7];
    const float* W_r2 = (const float*)d_in[8];
    const float* W_r3 = (const float*)d_in[9];
    const float* W_msg = (const float*)d_in[10];
    const float* W_skip = (const float*)d_in[11];

    float* out = (float*)d_out;                       // N x 576 final
    float* sc  = out + (size_t)N_NODES * MSG_DIM;     // N x 64

    float* wsf = (float*)d_ws;
    float* Wc = wsf;                          // 2048 floats
    float* h  = wsf + 2048;                   // N*64
    int* wsi   = (int*)(wsf + 2048 + (size_t)N_NODES * 64);
    int* counts = wsi;                        // N
    int* start  = wsi + N_NODES;              // N
    int* cursor = wsi + 2 * N_NODES;          // N
    float* rec  = (float*)(wsi + 3 * N_NODES);        // (E+16) * REC floats

    hipMemsetAsync(counts, 0, N_NODES * sizeof(int), stream);
    hist_kernel<<<1250, 256, 0, stream>>>(edge_index, counts);
    scan_radial_kernel<<<1, 1024, 0, stream>>>(counts, start, cursor,
                                               W_r0, W_r1, W_r2, W_r3, Wc, rec);
    scatter_nl<<<2500, 256, 0, stream>>>(
        edge_index, edge_feats, edge_attrs, cursor, rec,
        node_feats, W_lin1, h);
    gather_skip<<<10625, 256, 0, stream>>>(
        rec, h, Wc, W_msg, start, counts, out,
        node_attrs, W_skip, sc);
}